// Round 2
// baseline (405.600 us; speedup 1.0000x reference)
//
#include <hip/hip_runtime.h>
#include <stdint.h>
#include <stddef.h>

typedef unsigned short u16;
typedef unsigned int u32;
typedef __bf16 bf16x8 __attribute__((ext_vector_type(8)));
typedef float f32x4 __attribute__((ext_vector_type(4)));

#define TT 16384
#define NG 16
#define MAXTILES 272   // sum_g ceil(len_g/64) <= 16384/64 + 16

static __device__ __forceinline__ unsigned f2bf_u(float f) {
  unsigned u = __float_as_uint(f);
  return (u + 0x7fffu + ((u >> 16) & 1u)) >> 16;   // RNE fp32->bf16
}

// async global->LDS, 16B per lane; LDS dst is wave-uniform base + lane*16
static __device__ __forceinline__ void gl_lds16(const u16* g, u16* l) {
  __builtin_amdgcn_global_load_lds(
      (const __attribute__((address_space(1))) u32*)g,
      (__attribute__((address_space(3))) u32*)l, 16, 0, 0);
}

// ---------------------------------------------------------------------------
// prep: cast x (16384x512) and in_proj_w (1536x512) fp32->bf16; block 1120
// builds segment offsets and the (graph, q0) tile worklist from sorted batch.
// NOTE: harness passes integer inputs as int32 (NOT int64) -> batch is int*.
// seg layout (ints): [0]=n_tiles, [1..17]=seg_off, [32..303]=tile_g,
//                    [320..591]=tile_q0
// ---------------------------------------------------------------------------
#define NXF4 2097152   // 16384*512/4

__global__ __launch_bounds__(256) void prep_kernel(
    const float* __restrict__ x, const float* __restrict__ ipw,
    const int* __restrict__ batch,
    u16* __restrict__ xb, u16* __restrict__ ipwb, int* __restrict__ seg) {
  const int tid = threadIdx.x;
  if (blockIdx.x == 1120) {
    __shared__ int scnt[NG];
    if (tid < NG) scnt[tid] = 0;
    __syncthreads();
    for (int i = tid; i < TT; i += 256) atomicAdd(&scnt[batch[i] & (NG - 1)], 1);
    __syncthreads();
    if (tid == 0) {
      int off = 0, nt = 0;
      for (int g = 0; g < NG; ++g) { seg[1 + g] = off; off += scnt[g]; }
      seg[1 + NG] = off;
      for (int g = 0; g < NG; ++g)
        for (int q0 = 0; q0 < scnt[g]; q0 += 64) { seg[32 + nt] = g; seg[320 + nt] = q0; ++nt; }
      seg[0] = nt;
    }
    return;
  }
  const int base = blockIdx.x * 2048 + tid;
#pragma unroll
  for (int u = 0; u < 8; ++u) {
    int j = base + u * 256;
    float4 f;
    if (j < NXF4) f = ((const float4*)x)[j];
    else          f = ((const float4*)ipw)[j - NXF4];
    uint2 o;
    o.x = f2bf_u(f.x) | (f2bf_u(f.y) << 16);
    o.y = f2bf_u(f.z) | (f2bf_u(f.w) << 16);
    if (j < NXF4) ((uint2*)xb)[j] = o;
    else          ((uint2*)ipwb)[j - NXF4] = o;
  }
}

// ---------------------------------------------------------------------------
// wc: Wc[o][e] = sum_k Wl[o][k]*Wo[k][e]  (fp32 accumulate -> bf16)
//     bc[o]    = sum_k Wl[o][k]*bo[k] + bl[o]
// 128 blocks x 4 rows each.
// ---------------------------------------------------------------------------
__global__ __launch_bounds__(256) void wc_kernel(
    const float* __restrict__ Wl, const float* __restrict__ Wo,
    const float* __restrict__ bo, const float* __restrict__ bl,
    u16* __restrict__ Wc, float* __restrict__ bc) {
  const int tid = threadIdx.x;
  const int o0 = blockIdx.x << 2;
  __shared__ float sWl[4][512];
  __shared__ float red[256];
  for (int i = tid; i < 2048; i += 256)
    sWl[i >> 9][i & 511] = Wl[(o0 + (i >> 9)) * 512 + (i & 511)];
  __syncthreads();
  float a[4][2] = {};
#pragma unroll 2
  for (int k = 0; k < 512; ++k) {
    float w0 = Wo[k * 512 + tid];
    float w1 = Wo[k * 512 + tid + 256];
#pragma unroll
    for (int r = 0; r < 4; ++r) { a[r][0] += sWl[r][k] * w0; a[r][1] += sWl[r][k] * w1; }
  }
#pragma unroll
  for (int r = 0; r < 4; ++r) {
    Wc[(o0 + r) * 512 + tid]       = (u16)f2bf_u(a[r][0]);
    Wc[(o0 + r) * 512 + tid + 256] = (u16)f2bf_u(a[r][1]);
  }
  for (int r = 0; r < 4; ++r) {
    float p = 0.f;
    for (int k = tid; k < 512; k += 256) p += sWl[r][k] * bo[k];
    red[tid] = p;
    __syncthreads();
    for (int st = 128; st > 0; st >>= 1) {
      if (tid < st) red[tid] += red[tid + st];
      __syncthreads();
    }
    if (tid == 0) bc[o0 + r] = red[0] + bl[o0 + r];
    __syncthreads();
  }
}

// ---------------------------------------------------------------------------
// gemm_bt: C[M,N] = A[M,K] * Bt[N,K]^T + bias   (bf16 MFMA 16x16x32)
// 128x128 tile, BK=64, 4 waves (2x2), 4x4 16x16 acc frags per wave.
// LDS rows of 8x16B chunks, chunk XOR-swizzled by (row&7) -> conflict-free
// ds_read_b128 frag loads; staging via global_load_lds width 16.
// Requires M%128==0, N%128==0, K%64==0.
// ---------------------------------------------------------------------------
template <bool OUT_F32>
__global__ __launch_bounds__(256) void gemm_bt(
    const u16* __restrict__ A, const u16* __restrict__ Bt, void* __restrict__ C,
    const float* __restrict__ bias, int M, int N, int K) {
  const int nn = N >> 7;
  const int bm = blockIdx.x / nn, bn = blockIdx.x % nn;
  const int tid = threadIdx.x;
  const int w = tid >> 6, lane = tid & 63;
  const int quad = lane >> 4, l16 = lane & 15;
  const int wm = w >> 1, wn = w & 1;
  __shared__ __align__(16) u16 As[128 * 64];
  __shared__ __align__(16) u16 Bs[128 * 64];
  f32x4 acc[4][4];
#pragma unroll
  for (int mi = 0; mi < 4; ++mi)
#pragma unroll
    for (int ni = 0; ni < 4; ++ni) acc[mi][ni] = (f32x4){0.f, 0.f, 0.f, 0.f};
  const int sr = lane >> 3, scn = lane & 7;
  const int rowA0 = bm << 7, rowB0 = bn << 7;
  for (int kt = 0; kt < K; kt += 64) {
#pragma unroll
    for (int u = 0; u < 4; ++u) {
      int rbase = (w << 5) + (u << 3);     // wave w stages rows [w*32, w*32+32)
      int ml = rbase + sr;
      int ca = scn ^ (ml & 7);             // global chunk feeding stored pos scn
      gl_lds16(A  + (size_t)(rowA0 + ml) * K + kt + ca * 8, As + (rbase << 6));
      gl_lds16(Bt + (size_t)(rowB0 + ml) * K + kt + ca * 8, Bs + (rbase << 6));
    }
    __syncthreads();
#pragma unroll
    for (int ks = 0; ks < 2; ++ks) {
      bf16x8 af[4], bfv[4];
#pragma unroll
      for (int mi = 0; mi < 4; ++mi) {
        int r = (wm << 6) + (mi << 4) + l16;
        af[mi] = *(const bf16x8*)(As + (r << 6) + ((((ks << 2) + quad) ^ (r & 7)) << 3));
      }
#pragma unroll
      for (int ni = 0; ni < 4; ++ni) {
        int r = (wn << 6) + (ni << 4) + l16;
        bfv[ni] = *(const bf16x8*)(Bs + (r << 6) + ((((ks << 2) + quad) ^ (r & 7)) << 3));
      }
#pragma unroll
      for (int mi = 0; mi < 4; ++mi)
#pragma unroll
        for (int ni = 0; ni < 4; ++ni)
          acc[mi][ni] = __builtin_amdgcn_mfma_f32_16x16x32_bf16(af[mi], bfv[ni], acc[mi][ni], 0, 0, 0);
    }
    __syncthreads();
  }
  // epilogue: C/D layout col=lane&15, row=quad*4+reg
#pragma unroll
  for (int mi = 0; mi < 4; ++mi) {
#pragma unroll
    for (int ni = 0; ni < 4; ++ni) {
      int row = rowA0 + (wm << 6) + (mi << 4) + (quad << 2);
      int col = rowB0 + (wn << 6) + (ni << 4) + l16;
      float bv = bias[col];
#pragma unroll
      for (int r = 0; r < 4; ++r) {
        float v = acc[mi][ni][r] + bv;
        if (OUT_F32) ((float*)C)[(size_t)(row + r) * N + col] = v;
        else         ((u16*)C)[(size_t)(row + r) * N + col] = (u16)f2bf_u(v);
      }
    }
  }
}

// ---------------------------------------------------------------------------
// attn: flash attention over one (q-tile of 64, head) pair of one segment.
// qkv: [T][1536] bf16 (q|k|v each 512). ctx out: [T][512] bf16.
// 4 waves; wave w owns q rows w*16..w*16+15. Q frags live in registers.
// K tile [key][d] and V tile transposed [d][key] staged in swizzled LDS.
// Online softmax in log2 domain; P -> per-wave LDS -> A-operand frags.
// ---------------------------------------------------------------------------
__global__ __launch_bounds__(256) void attn_kernel(
    const u16* __restrict__ qkv, u16* __restrict__ ctx, const int* __restrict__ seg) {
  const int bx = blockIdx.x;
  if (bx >= seg[0]) return;
  const int h = blockIdx.y;
  const int g = seg[32 + bx];
  const int q0 = seg[320 + bx];
  const int s0 = seg[1 + g];
  const int len = seg[2 + g] - s0;
  const int tid = threadIdx.x;
  const int w = tid >> 6, lane = tid & 63;
  const int quad = lane >> 4, l16 = lane & 15;

  __shared__ __align__(16) u16 Ks[64 * 64];
  __shared__ __align__(16) u16 Vt[64 * 64];
  __shared__ __align__(16) u16 Ps[4 * 16 * 64];

  // Q fragments (A-operand layout: A[m=lane&15][k=quad*8+j]), masked load
  const int qr = (w << 4) + l16;
  bf16x8 afq[2];
#pragma unroll
  for (int ks = 0; ks < 2; ++ks) {
    uint4 tmp = {0u, 0u, 0u, 0u};
    if (q0 + qr < len)
      tmp = *(const uint4*)(qkv + (size_t)(s0 + q0 + qr) * 1536 + h * 64 + ((ks << 2) + quad) * 8);
    afq[ks] = __builtin_bit_cast(bf16x8, tmp);
  }

  f32x4 mrow = {-1e30f, -1e30f, -1e30f, -1e30f};
  f32x4 lrow = {0.f, 0.f, 0.f, 0.f};
  f32x4 O[4];
#pragma unroll
  for (int dt = 0; dt < 4; ++dt) O[dt] = (f32x4){0.f, 0.f, 0.f, 0.f};
  const float sc = 0.18033688011112042f;  // log2(e)/sqrt(64)

  for (int kv0 = 0; kv0 < len; kv0 += 64) {
    __syncthreads();
    // stage K [key][d], chunk-swizzled rows, zero-fill tail
#pragma unroll
    for (int i = 0; i < 2; ++i) {
      int idx = (i << 8) + tid, r = idx >> 3, c = idx & 7;
      uint4 v = {0u, 0u, 0u, 0u};
      if (kv0 + r < len)
        v = *(const uint4*)(qkv + (size_t)(s0 + kv0 + r) * 1536 + 512 + h * 64 + c * 8);
      *(uint4*)(Ks + (r << 6) + ((c ^ (r & 7)) << 3)) = v;
    }
    // stage V transposed: Vt[d][key]; lane order t-fast -> conflict-free writes
#pragma unroll
    for (int i = 0; i < 2; ++i) {
      int idx = (i << 8) + tid, t = idx & 63, c = idx >> 6;
      uint4 v = {0u, 0u, 0u, 0u};
      if (kv0 + t < len)
        v = *(const uint4*)(qkv + (size_t)(s0 + kv0 + t) * 1536 + 1024 + h * 64 + c * 8);
      const u16* pv = (const u16*)&v;
#pragma unroll
      for (int j = 0; j < 8; ++j)
        Vt[((c << 3) + j) * 64 + (((t >> 3) ^ j) << 3) + (t & 7)] = pv[j];
    }
    __syncthreads();

    // S = Q K^T  (wave: 16 q rows x 64 keys)
    f32x4 s[4];
#pragma unroll
    for (int nt = 0; nt < 4; ++nt) s[nt] = (f32x4){0.f, 0.f, 0.f, 0.f};
#pragma unroll
    for (int ks = 0; ks < 2; ++ks) {
#pragma unroll
      for (int nt = 0; nt < 4; ++nt) {
        int kr = (nt << 4) + l16;
        bf16x8 bk = *(const bf16x8*)(Ks + (kr << 6) + ((((ks << 2) + quad) ^ (kr & 7)) << 3));
        s[nt] = __builtin_amdgcn_mfma_f32_16x16x32_bf16(afq[ks], bk, s[nt], 0, 0, 0);
      }
    }
    // scale to log2 domain + key mask
#pragma unroll
    for (int nt = 0; nt < 4; ++nt) {
      float msk = ((kv0 + (nt << 4) + l16) < len) ? 0.f : -1e30f;
#pragma unroll
      for (int r = 0; r < 4; ++r) s[nt][r] = s[nt][r] * sc + msk;
    }
    // per-row (row = quad*4+r) online softmax; cols live across 16 lanes/quad
    f32x4 rm = s[0];
#pragma unroll
    for (int nt = 1; nt < 4; ++nt)
#pragma unroll
      for (int r = 0; r < 4; ++r) rm[r] = fmaxf(rm[r], s[nt][r]);
#pragma unroll
    for (int off = 1; off < 16; off <<= 1)
#pragma unroll
      for (int r = 0; r < 4; ++r) rm[r] = fmaxf(rm[r], __shfl_xor(rm[r], off));
    f32x4 mnew, alpha;
#pragma unroll
    for (int r = 0; r < 4; ++r) {
      mnew[r] = fmaxf(mrow[r], rm[r]);
      alpha[r] = __builtin_amdgcn_exp2f(mrow[r] - mnew[r]);
    }
    f32x4 rs = {0.f, 0.f, 0.f, 0.f};
#pragma unroll
    for (int nt = 0; nt < 4; ++nt)
#pragma unroll
      for (int r = 0; r < 4; ++r) {
        float p = __builtin_amdgcn_exp2f(s[nt][r] - mnew[r]);
        s[nt][r] = p;
        rs[r] += p;
      }
#pragma unroll
    for (int off = 1; off < 16; off <<= 1)
#pragma unroll
      for (int r = 0; r < 4; ++r) rs[r] += __shfl_xor(rs[r], off);
#pragma unroll
    for (int r = 0; r < 4; ++r) lrow[r] = lrow[r] * alpha[r] + rs[r];
    mrow = mnew;
#pragma unroll
    for (int dt = 0; dt < 4; ++dt) O[dt] *= alpha;

    // P (C-layout) -> per-wave LDS in swizzled A-layout; same-wave roundtrip,
    // no barrier needed (DS ops are in-order within a wave)
    u16* Pw = Ps + (w << 10);
#pragma unroll
    for (int nt = 0; nt < 4; ++nt)
#pragma unroll
      for (int r = 0; r < 4; ++r) {
        int prow = (quad << 2) + r, kcol = (nt << 4) + l16;
        Pw[(prow << 6) + (((kcol >> 3) ^ (prow & 7)) << 3) + (kcol & 7)] = (u16)f2bf_u(s[nt][r]);
      }
    // O += P V
#pragma unroll
    for (int ks = 0; ks < 2; ++ks) {
      bf16x8 ap = *(const bf16x8*)(Pw + (l16 << 6) + ((((ks << 2) + quad) ^ (l16 & 7)) << 3));
#pragma unroll
      for (int dt = 0; dt < 4; ++dt) {
        int vr = (dt << 4) + l16;
        bf16x8 bv = *(const bf16x8*)(Vt + (vr << 6) + ((((ks << 2) + quad) ^ (vr & 7)) << 3));
        O[dt] = __builtin_amdgcn_mfma_f32_16x16x32_bf16(ap, bv, O[dt], 0, 0, 0);
      }
    }
  }
  // normalize + store
  f32x4 inv;
#pragma unroll
  for (int r = 0; r < 4; ++r) inv[r] = 1.f / lrow[r];
#pragma unroll
  for (int dt = 0; dt < 4; ++dt)
#pragma unroll
    for (int r = 0; r < 4; ++r) {
      int ql = (w << 4) + (quad << 2) + r;
      if (q0 + ql < len)
        ctx[(size_t)(s0 + q0 + ql) * 512 + h * 64 + (dt << 4) + l16] = (u16)f2bf_u(O[dt][r] * inv[r]);
    }
}

// ---------------------------------------------------------------------------
extern "C" void kernel_launch(void* const* d_in, const int* in_sizes, int n_in,
                              void* d_out, int out_size, void* d_ws, size_t ws_size,
                              hipStream_t stream) {
  const float* x = (const float*)d_in[0];
  const int* batch = (const int*)d_in[1];   // harness passes integers as int32
  const float* ipw = (const float*)d_in[2];
  const float* ipb = (const float*)d_in[3];
  const float* opw = (const float*)d_in[4];
  const float* opb = (const float*)d_in[5];
  const float* lw = (const float*)d_in[6];
  const float* lb = (const float*)d_in[7];
  float* out = (float*)d_out;
  char* ws = (char*)d_ws;

  u16* xb   = (u16*)(ws + 0);              // 16 MB (x bf16)
  u16* ctxb = (u16*)(ws + 0);              // aliases xb: disjoint liveness
  u16* qkvb = (u16*)(ws + 16777216);       // 48 MB
  u16* ipwb = (u16*)(ws + 67108864);       // 1.5 MB
  u16* wcb  = (u16*)(ws + 68681728);       // 0.5 MB
  float* bc = (float*)(ws + 69206016);     // 2 KB
  int* seg  = (int*)(ws + 69208064);       // 4 KB

  prep_kernel<<<1121, 256, 0, stream>>>(x, ipw, batch, xb, ipwb, seg);
  wc_kernel<<<128, 256, 0, stream>>>(lw, opw, opb, lb, wcb, bc);
  gemm_bt<false><<<128 * 12, 256, 0, stream>>>(xb, ipwb, qkvb, ipb, TT, 1536, 512);
  attn_kernel<<<dim3(MAXTILES, 8), 256, 0, stream>>>(qkvb, ctxb, seg);
  gemm_bt<true><<<128 * 4, 256, 0, stream>>>(ctxb, wcb, out, bc, TT, 512, 512);
  (void)in_sizes; (void)n_in; (void)out_size; (void)ws_size;
}

// Round 4
// 361.832 us; speedup vs baseline: 1.1210x; 1.1210x over previous
//
#include <hip/hip_runtime.h>
#include <stdint.h>
#include <stddef.h>

typedef unsigned short u16;
typedef unsigned int u32;
typedef __bf16 bf16x8 __attribute__((ext_vector_type(8)));
typedef float f32x4 __attribute__((ext_vector_type(4)));

#define TT 16384
#define NG 16
#define MAXT 160   // sum_g ceil(len_g/128) <= 128+16 = 144

static __device__ __forceinline__ unsigned f2bf_u(float f) {
  unsigned u = __float_as_uint(f);
  return (u + 0x7fffu + ((u >> 16) & 1u)) >> 16;   // RNE fp32->bf16
}

// async global->LDS, 16B per lane; LDS dst is wave-uniform base + lane*16
static __device__ __forceinline__ void gl_lds16(const u16* g, u16* l) {
  __builtin_amdgcn_global_load_lds(
      (const __attribute__((address_space(1))) u32*)g,
      (__attribute__((address_space(3))) u32*)l, 16, 0, 0);
}

// DPP cross-lane within 16-lane row (VALU pipe, no DS traffic)
template <int CTRL>
static __device__ __forceinline__ float dppf(float x) {
  return __int_as_float(__builtin_amdgcn_mov_dpp(__float_as_int(x), CTRL, 0xF, 0xF, true));
}
// xor1=quad_perm(1,0,3,2)=0xB1, xor2=quad_perm(2,3,0,1)=0x4E,
// ror4=0x124, ror8=0x128 — together a full 16-lane reduction.

// ---------------------------------------------------------------------------
// prep: cast x (16384x512) and in_proj_w (1536x512) fp32->bf16; block 1120
// builds segment offsets and the (graph, q0 step 128) tile worklist.
// seg layout (ints): [0]=n_tiles, [1..17]=seg_off, [32..]=tile_g, [320..]=tile_q0
// ---------------------------------------------------------------------------
#define NXF4 2097152   // 16384*512/4

__global__ __launch_bounds__(256) void prep_kernel(
    const float* __restrict__ x, const float* __restrict__ ipw,
    const int* __restrict__ batch,
    u16* __restrict__ xb, u16* __restrict__ ipwb, int* __restrict__ seg) {
  const int tid = threadIdx.x;
  if (blockIdx.x == 1120) {
    __shared__ int scnt[NG];
    if (tid < NG) scnt[tid] = 0;
    __syncthreads();
    for (int i = tid; i < TT; i += 256) atomicAdd(&scnt[batch[i] & (NG - 1)], 1);
    __syncthreads();
    if (tid == 0) {
      int off = 0, nt = 0;
      for (int g = 0; g < NG; ++g) { seg[1 + g] = off; off += scnt[g]; }
      seg[1 + NG] = off;
      for (int g = 0; g < NG; ++g)
        for (int q0 = 0; q0 < scnt[g]; q0 += 128) { seg[32 + nt] = g; seg[320 + nt] = q0; ++nt; }
      seg[0] = nt;
    }
    return;
  }
  const int base = blockIdx.x * 2048 + tid;
#pragma unroll
  for (int u = 0; u < 8; ++u) {
    int j = base + u * 256;
    float4 f;
    if (j < NXF4) f = ((const float4*)x)[j];
    else          f = ((const float4*)ipw)[j - NXF4];
    uint2 o;
    o.x = f2bf_u(f.x) | (f2bf_u(f.y) << 16);
    o.y = f2bf_u(f.z) | (f2bf_u(f.w) << 16);
    if (j < NXF4) ((uint2*)xb)[j] = o;
    else          ((uint2*)ipwb)[j - NXF4] = o;
  }
}

// ---------------------------------------------------------------------------
// wc: Wc[o][e] = sum_k Wl[o][k]*Wo[k][e], bc[o] = sum_k Wl[o][k]*bo[k]+bl[o]
// 256 blocks: (o-group of 4 rows) x (column half of 256).
// ---------------------------------------------------------------------------
__global__ __launch_bounds__(256) void wc_kernel(
    const float* __restrict__ Wl, const float* __restrict__ Wo,
    const float* __restrict__ bo, const float* __restrict__ bl,
    u16* __restrict__ Wc, float* __restrict__ bc) {
  const int tid = threadIdx.x;
  const int o0 = (blockIdx.x >> 1) << 2;
  const int ch = (blockIdx.x & 1) << 8;
  __shared__ float sWl[4][512];
  __shared__ float red[256];
  for (int i = tid; i < 2048; i += 256)
    sWl[i >> 9][i & 511] = Wl[(o0 + (i >> 9)) * 512 + (i & 511)];
  __syncthreads();
  const int col = ch + tid;
  float a[4] = {};
#pragma unroll 4
  for (int k = 0; k < 512; ++k) {
    float w0 = Wo[k * 512 + col];
#pragma unroll
    for (int r = 0; r < 4; ++r) a[r] += sWl[r][k] * w0;
  }
#pragma unroll
  for (int r = 0; r < 4; ++r) Wc[(o0 + r) * 512 + col] = (u16)f2bf_u(a[r]);
  if (ch == 0) {
    for (int r = 0; r < 4; ++r) {
      float p = 0.f;
      for (int k = tid; k < 512; k += 256) p += sWl[r][k] * bo[k];
      red[tid] = p;
      __syncthreads();
      for (int st = 128; st > 0; st >>= 1) {
        if (tid < st) red[tid] += red[tid + st];
        __syncthreads();
      }
      if (tid == 0) bc[o0 + r] = red[0] + bl[o0 + r];
      __syncthreads();
    }
  }
}

// ---------------------------------------------------------------------------
// gemm_bt: C[M,N] = A[M,K] * Bt[N,K]^T + bias   (bf16 MFMA 16x16x32)
// 128x128 tile, BK=64, 4 waves, 4x4 acc frags; swizzled LDS; gl_lds16 staging.
// BIAS_ROW: bias indexed by output row (used for Vt = Wv * X^T + bv[row]).
// ---------------------------------------------------------------------------
template <bool OUT_F32, bool BIAS_ROW>
__global__ __launch_bounds__(256) void gemm_bt(
    const u16* __restrict__ A, const u16* __restrict__ Bt, void* __restrict__ C,
    const float* __restrict__ bias, int M, int N, int K) {
  const int nn = N >> 7;
  const int bm = blockIdx.x / nn, bn = blockIdx.x % nn;
  const int tid = threadIdx.x;
  const int w = tid >> 6, lane = tid & 63;
  const int quad = lane >> 4, l16 = lane & 15;
  const int wm = w >> 1, wn = w & 1;
  __shared__ __align__(16) u16 As[128 * 64];
  __shared__ __align__(16) u16 Bs[128 * 64];
  f32x4 acc[4][4];
#pragma unroll
  for (int mi = 0; mi < 4; ++mi)
#pragma unroll
    for (int ni = 0; ni < 4; ++ni) acc[mi][ni] = (f32x4){0.f, 0.f, 0.f, 0.f};
  const int sr = lane >> 3, scn = lane & 7;
  const int rowA0 = bm << 7, rowB0 = bn << 7;
  for (int kt = 0; kt < K; kt += 64) {
#pragma unroll
    for (int u = 0; u < 4; ++u) {
      int rbase = (w << 5) + (u << 3);
      int ml = rbase + sr;
      int ca = scn ^ (ml & 7);
      gl_lds16(A  + (size_t)(rowA0 + ml) * K + kt + ca * 8, As + (rbase << 6));
      gl_lds16(Bt + (size_t)(rowB0 + ml) * K + kt + ca * 8, Bs + (rbase << 6));
    }
    __syncthreads();
#pragma unroll
    for (int ks = 0; ks < 2; ++ks) {
      bf16x8 af[4], bfv[4];
#pragma unroll
      for (int mi = 0; mi < 4; ++mi) {
        int r = (wm << 6) + (mi << 4) + l16;
        af[mi] = *(const bf16x8*)(As + (r << 6) + ((((ks << 2) + quad) ^ (r & 7)) << 3));
      }
#pragma unroll
      for (int ni = 0; ni < 4; ++ni) {
        int r = (wn << 6) + (ni << 4) + l16;
        bfv[ni] = *(const bf16x8*)(Bs + (r << 6) + ((((ks << 2) + quad) ^ (r & 7)) << 3));
      }
#pragma unroll
      for (int mi = 0; mi < 4; ++mi)
#pragma unroll
        for (int ni = 0; ni < 4; ++ni)
          acc[mi][ni] = __builtin_amdgcn_mfma_f32_16x16x32_bf16(af[mi], bfv[ni], acc[mi][ni], 0, 0, 0);
    }
    __syncthreads();
  }
#pragma unroll
  for (int mi = 0; mi < 4; ++mi) {
#pragma unroll
    for (int ni = 0; ni < 4; ++ni) {
      int row = rowA0 + (wm << 6) + (mi << 4) + (quad << 2);
      int col = rowB0 + (wn << 6) + (ni << 4) + l16;
      float bvc = BIAS_ROW ? 0.f : bias[col];
#pragma unroll
      for (int r = 0; r < 4; ++r) {
        float v = acc[mi][ni][r] + (BIAS_ROW ? bias[row + r] : bvc);
        if (OUT_F32) ((float*)C)[(size_t)(row + r) * N + col] = v;
        else         ((u16*)C)[(size_t)(row + r) * N + col] = (u16)f2bf_u(v);
      }
    }
  }
}

// ---------------------------------------------------------------------------
// attn v2: one block = (q-tile of 128, head). 4 waves, 32 q rows each.
// qk: [T][1024] bf16 (q|k). vt: [512][T] bf16 (pre-transposed V, h*64+d rows).
// K and Vt staged by swizzled gl_lds16 (kv window starts at -(s0&7) so all
// global 16B chunks stay aligned). V chunks are redirected ONLY when fully
// masked (st >= len): partially-valid tail chunks keep their true address
// (may overrun segment end by <=7 masked tokens — finite, in-bounds of ws).
// Softmax reductions via DPP. P pair-packed to ds_write_b32.
// ---------------------------------------------------------------------------
__global__ __launch_bounds__(256) void attn_kernel(
    const u16* __restrict__ qk, const u16* __restrict__ vt,
    u16* __restrict__ ctx, const int* __restrict__ seg) {
  const int bx = blockIdx.x;
  if (bx >= seg[0]) return;
  const int h = blockIdx.y;
  const int g = seg[32 + bx], q0 = seg[320 + bx];
  const int s0 = seg[1 + g], len = seg[2 + g] - s0;
  const int tid = threadIdx.x, w = tid >> 6, lane = tid & 63;
  const int quad = lane >> 4, l16 = lane & 15;

  __shared__ __align__(16) u16 Ks[64 * 64];
  __shared__ __align__(16) u16 Vs[64 * 64];
  __shared__ __align__(16) u16 Ps[4 * 32 * 64];   // per-wave P (2 m-tiles)

  // Q fragments, 32 rows/wave (mt=0,1), masked to zero beyond len
  bf16x8 afq[2][2];
#pragma unroll
  for (int mt = 0; mt < 2; ++mt)
#pragma unroll
    for (int ks = 0; ks < 2; ++ks) {
      int ql = (w << 5) + (mt << 4) + l16;
      uint4 tmp = {0u, 0u, 0u, 0u};
      if (q0 + ql < len)
        tmp = *(const uint4*)(qk + (size_t)(s0 + q0 + ql) * 1024 + (h << 6) + (((ks << 2) + quad) << 3));
      afq[mt][ks] = __builtin_bit_cast(bf16x8, tmp);
    }

  f32x4 mrow[2], lrow[2], O[2][4];
#pragma unroll
  for (int mt = 0; mt < 2; ++mt) {
    mrow[mt] = (f32x4){-1e30f, -1e30f, -1e30f, -1e30f};
    lrow[mt] = (f32x4){0.f, 0.f, 0.f, 0.f};
#pragma unroll
    for (int dt = 0; dt < 4; ++dt) O[mt][dt] = (f32x4){0.f, 0.f, 0.f, 0.f};
  }
  const float scl = 0.18033688011112042f;  // log2(e)/sqrt(64)
  const int delta = s0 & 7;                 // alignment shift of kv window
  const int srl = lane >> 3, sc = lane & 7;
  int vcl = ((len - 8 + delta) & ~7) - delta;   // safe aligned start, +8 <= len
  if (vcl < -delta) vcl = -delta;

  for (int kv0 = -delta; kv0 < len; kv0 += 64) {
    __syncthreads();
#pragma unroll
    for (int u = 0; u < 2; ++u) {
      const int rb = (w << 4) + (u << 3);
      int r = rb + srl;
      int ca = sc ^ (r & 7);
      int rg = kv0 + r; rg = rg < len - 1 ? rg : len - 1;   // clamp (finite, masked)
      gl_lds16(qk + (size_t)(s0 + rg) * 1024 + 512 + (h << 6) + ca * 8, Ks + (rb << 6));
      int st = kv0 + ca * 8;
      st = (st < len) ? st : vcl;   // redirect ONLY fully-masked chunks
      gl_lds16(vt + (size_t)((h << 6) + r) * TT + s0 + st, Vs + (rb << 6));
    }
    __syncthreads();

    // S = Q K^T
    f32x4 s[2][4];
#pragma unroll
    for (int mt = 0; mt < 2; ++mt)
#pragma unroll
      for (int nt = 0; nt < 4; ++nt) s[mt][nt] = (f32x4){0.f, 0.f, 0.f, 0.f};
#pragma unroll
    for (int ks = 0; ks < 2; ++ks) {
      bf16x8 bk[4];
#pragma unroll
      for (int nt = 0; nt < 4; ++nt) {
        int kr = (nt << 4) + l16;
        bk[nt] = *(const bf16x8*)(Ks + (kr << 6) + ((((ks << 2) + quad) ^ (kr & 7)) << 3));
      }
#pragma unroll
      for (int mt = 0; mt < 2; ++mt)
#pragma unroll
        for (int nt = 0; nt < 4; ++nt)
          s[mt][nt] = __builtin_amdgcn_mfma_f32_16x16x32_bf16(afq[mt][ks], bk[nt], s[mt][nt], 0, 0, 0);
    }
    // scale to log2 domain + key mask (handles both kv0<0 head and len tail)
#pragma unroll
    for (int nt = 0; nt < 4; ++nt) {
      int ki = kv0 + (nt << 4) + l16;
      float msk = ((unsigned)ki < (unsigned)len) ? 0.f : -1e30f;
#pragma unroll
      for (int mt = 0; mt < 2; ++mt)
#pragma unroll
        for (int r = 0; r < 4; ++r) s[mt][nt][r] = s[mt][nt][r] * scl + msk;
    }
#pragma unroll
    for (int mt = 0; mt < 2; ++mt) {
      f32x4 rm = s[mt][0];
#pragma unroll
      for (int nt = 1; nt < 4; ++nt)
#pragma unroll
        for (int r = 0; r < 4; ++r) rm[r] = fmaxf(rm[r], s[mt][nt][r]);
#pragma unroll
      for (int r = 0; r < 4; ++r) {
        rm[r] = fmaxf(rm[r], dppf<0xB1>(rm[r]));
        rm[r] = fmaxf(rm[r], dppf<0x4E>(rm[r]));
        rm[r] = fmaxf(rm[r], dppf<0x124>(rm[r]));
        rm[r] = fmaxf(rm[r], dppf<0x128>(rm[r]));
      }
      f32x4 mnew, alpha;
#pragma unroll
      for (int r = 0; r < 4; ++r) {
        mnew[r] = fmaxf(mrow[mt][r], rm[r]);
        alpha[r] = __builtin_amdgcn_exp2f(mrow[mt][r] - mnew[r]);
      }
      f32x4 rs = {0.f, 0.f, 0.f, 0.f};
#pragma unroll
      for (int nt = 0; nt < 4; ++nt)
#pragma unroll
        for (int r = 0; r < 4; ++r) {
          float p = __builtin_amdgcn_exp2f(s[mt][nt][r] - mnew[r]);
          s[mt][nt][r] = p;
          rs[r] += p;
        }
#pragma unroll
      for (int r = 0; r < 4; ++r) {
        rs[r] += dppf<0xB1>(rs[r]);
        rs[r] += dppf<0x4E>(rs[r]);
        rs[r] += dppf<0x124>(rs[r]);
        rs[r] += dppf<0x128>(rs[r]);
        lrow[mt][r] = lrow[mt][r] * alpha[r] + rs[r];
      }
      mrow[mt] = mnew;
#pragma unroll
      for (int dt = 0; dt < 4; ++dt) O[mt][dt] *= alpha;

      // P pack pairs via DPP xor1, even lanes write b32 (swizzled A-layout)
      u16* Pw = Ps + (w << 11) + (mt << 10);
#pragma unroll
      for (int nt = 0; nt < 4; ++nt)
#pragma unroll
        for (int r = 0; r < 4; ++r) {
          unsigned a = f2bf_u(s[mt][nt][r]);
          unsigned b = (unsigned)__builtin_amdgcn_mov_dpp((int)a, 0xB1, 0xF, 0xF, true);
          if (!(l16 & 1)) {
            int prow = (quad << 2) + r, kc = (nt << 4) + l16;
            *(u32*)(Pw + (prow << 6) + (((kc >> 3) ^ (prow & 7)) << 3) + (kc & 7)) = (b << 16) | a;
          }
        }
    }
    // O += P V   (same-wave LDS roundtrip, DS ops in-order, no barrier)
#pragma unroll
    for (int ks = 0; ks < 2; ++ks) {
      bf16x8 bv[4], ap[2];
#pragma unroll
      for (int dt = 0; dt < 4; ++dt) {
        int vr = (dt << 4) + l16;
        bv[dt] = *(const bf16x8*)(Vs + (vr << 6) + ((((ks << 2) + quad) ^ (vr & 7)) << 3));
      }
#pragma unroll
      for (int mt = 0; mt < 2; ++mt)
        ap[mt] = *(const bf16x8*)(Ps + (w << 11) + (mt << 10) + (l16 << 6) + ((((ks << 2) + quad) ^ (l16 & 7)) << 3));
#pragma unroll
      for (int mt = 0; mt < 2; ++mt)
#pragma unroll
        for (int dt = 0; dt < 4; ++dt)
          O[mt][dt] = __builtin_amdgcn_mfma_f32_16x16x32_bf16(ap[mt], bv[dt], O[mt][dt], 0, 0, 0);
    }
  }

#pragma unroll
  for (int mt = 0; mt < 2; ++mt) {
    f32x4 inv;
#pragma unroll
    for (int r = 0; r < 4; ++r) inv[r] = 1.f / lrow[mt][r];
#pragma unroll
    for (int dt = 0; dt < 4; ++dt)
#pragma unroll
      for (int r = 0; r < 4; ++r) {
        int ql = (w << 5) + (mt << 4) + (quad << 2) + r;
        if (q0 + ql < len)
          ctx[(size_t)(s0 + q0 + ql) * 512 + (h << 6) + (dt << 4) + l16] = (u16)f2bf_u(O[mt][dt][r] * inv[r]);
      }
  }
}

// ---------------------------------------------------------------------------
extern "C" void kernel_launch(void* const* d_in, const int* in_sizes, int n_in,
                              void* d_out, int out_size, void* d_ws, size_t ws_size,
                              hipStream_t stream) {
  const float* x = (const float*)d_in[0];
  const int* batch = (const int*)d_in[1];   // harness passes integers as int32
  const float* ipw = (const float*)d_in[2];
  const float* ipb = (const float*)d_in[3];
  const float* opw = (const float*)d_in[4];
  const float* opb = (const float*)d_in[5];
  const float* lw = (const float*)d_in[6];
  const float* lb = (const float*)d_in[7];
  float* out = (float*)d_out;
  char* ws = (char*)d_ws;

  u16* xb   = (u16*)(ws + 0);              // 16 MB (x bf16)
  u16* ctxb = (u16*)(ws + 0);              // aliases xb (disjoint liveness)
  u16* qkb  = (u16*)(ws + 16777216);       // 32 MB: [T][1024] q|k
  u16* vtb  = (u16*)(ws + 50331648);       // 16 MB: [512][T] V^T
  u16* ipwb = (u16*)(ws + 67108864);       // 1.5 MB
  u16* wcb  = (u16*)(ws + 68681728);       // 0.5 MB
  float* bc = (float*)(ws + 69206016);     // 2 KB
  int* seg  = (int*)(ws + 69208064);       // 4 KB

  prep_kernel<<<1121, 256, 0, stream>>>(x, ipw, batch, xb, ipwb, seg);
  wc_kernel<<<256, 256, 0, stream>>>(lw, opw, opb, lb, wcb, bc);
  // QK = X * W_qk^T + b_qk   -> [T][1024]
  gemm_bt<false, false><<<128 * 8, 256, 0, stream>>>(xb, ipwb, qkb, ipb, TT, 1024, 512);
  // V^T = Wv * X^T + bv[row] -> [512][T]
  gemm_bt<false, true><<<4 * 128, 256, 0, stream>>>(ipwb + 1024 * 512, xb, vtb, ipb + 1024, 512, TT, 512);
  attn_kernel<<<dim3(MAXT, 8), 256, 0, stream>>>(qkb, vtb, ctxb, seg);
  gemm_bt<true, false><<<128 * 4, 256, 0, stream>>>(ctxb, wcb, out, bc, TT, 512, 512);
  (void)in_sizes; (void)n_in; (void)out_size; (void)ws_size;
}

// Round 5
// 345.374 us; speedup vs baseline: 1.1744x; 1.0477x over previous
//
#include <hip/hip_runtime.h>
#include <stdint.h>
#include <stddef.h>

typedef unsigned short u16;
typedef unsigned int u32;
typedef __bf16 bf16x8 __attribute__((ext_vector_type(8)));
typedef float f32x4 __attribute__((ext_vector_type(4)));

#define TT 16384
#define NG 16
#define MAXT 160   // sum_g ceil(len_g/128) <= 128+16 = 144
#define SCL 0.18033688011112042f   // log2(e)/sqrt(64)

static __device__ __forceinline__ unsigned f2bf_u(float f) {
  unsigned u = __float_as_uint(f);
  return (u + 0x7fffu + ((u >> 16) & 1u)) >> 16;   // RNE fp32->bf16
}

// async global->LDS, 16B per lane; LDS dst is wave-uniform base + lane*16
static __device__ __forceinline__ void gl_lds16(const u16* g, u16* l) {
  __builtin_amdgcn_global_load_lds(
      (const __attribute__((address_space(1))) u32*)g,
      (__attribute__((address_space(3))) u32*)l, 16, 0, 0);
}

// DPP cross-lane within 16-lane row (VALU pipe, no DS traffic)
template <int CTRL>
static __device__ __forceinline__ float dppf(float x) {
  return __int_as_float(__builtin_amdgcn_mov_dpp(__float_as_int(x), CTRL, 0xF, 0xF, true));
}
// xor1=0xB1, xor2=0x4E, ror4=0x124, ror8=0x128 -> full 16-lane reduction

// ---------------------------------------------------------------------------
// prep: cast x and in_proj_w fp32->bf16 (Wq rows pre-scaled by SCL so QK^T
// emerges in log2 domain); block 1120 builds seg worklist + scaled qk bias.
// seg: [0]=n_tiles, [1..17]=seg_off, [32..]=tile_g, [320..]=tile_q0
// ---------------------------------------------------------------------------
#define NXF4 2097152   // 16384*512/4
#define NWQ4 65536     // 512*512/4 (Wq rows of in_proj_w)

__global__ __launch_bounds__(256) void prep_kernel(
    const float* __restrict__ x, const float* __restrict__ ipw,
    const int* __restrict__ batch, const float* __restrict__ ipb,
    u16* __restrict__ xb, u16* __restrict__ ipwb, float* __restrict__ bqk,
    int* __restrict__ seg) {
  const int tid = threadIdx.x;
  if (blockIdx.x == 1120) {
    __shared__ int scnt[NG];
    if (tid < NG) scnt[tid] = 0;
    __syncthreads();
    for (int i = tid; i < TT; i += 256) atomicAdd(&scnt[batch[i] & (NG - 1)], 1);
    for (int i = tid; i < 1024; i += 256) bqk[i] = ipb[i] * (i < 512 ? SCL : 1.f);
    __syncthreads();
    if (tid == 0) {
      int off = 0, nt = 0;
      for (int g = 0; g < NG; ++g) { seg[1 + g] = off; off += scnt[g]; }
      seg[1 + NG] = off;
      for (int g = 0; g < NG; ++g)
        for (int q0 = 0; q0 < scnt[g]; q0 += 128) { seg[32 + nt] = g; seg[320 + nt] = q0; ++nt; }
      seg[0] = nt;
    }
    return;
  }
  const int base = blockIdx.x * 2048 + tid;
#pragma unroll
  for (int u = 0; u < 8; ++u) {
    int j = base + u * 256;
    float4 f;
    if (j < NXF4) f = ((const float4*)x)[j];
    else          f = ((const float4*)ipw)[j - NXF4];
    if (j >= NXF4 && j < NXF4 + NWQ4) { f.x *= SCL; f.y *= SCL; f.z *= SCL; f.w *= SCL; }
    uint2 o;
    o.x = f2bf_u(f.x) | (f2bf_u(f.y) << 16);
    o.y = f2bf_u(f.z) | (f2bf_u(f.w) << 16);
    if (j < NXF4) ((uint2*)xb)[j] = o;
    else          ((uint2*)ipwb)[j - NXF4] = o;
  }
}

// ---------------------------------------------------------------------------
// wc: Wc = Wl*Wo (fp32 acc -> bf16), bc = Wl*bo + bl.
// 128 blocks = 32 row-groups(16) x 4 col-groups(128); Wl staged in LDS.
// ---------------------------------------------------------------------------
__global__ __launch_bounds__(256) void wc_kernel(
    const float* __restrict__ Wl, const float* __restrict__ Wo,
    const float* __restrict__ bo, const float* __restrict__ bl,
    u16* __restrict__ Wc, float* __restrict__ bc) {
  const int tid = threadIdx.x;
  const int r0 = (blockIdx.x >> 2) << 4;
  const int c0 = (blockIdx.x & 3) << 7;
  const int col = c0 + (tid & 127), rh = (tid >> 7) << 3;
  __shared__ float sWl[16][512];
  __shared__ float red[256];
  for (int i = tid; i < 16 * 512; i += 256)
    sWl[i >> 9][i & 511] = Wl[(r0 + (i >> 9)) * 512 + (i & 511)];
  __syncthreads();
  float a[8] = {};
#pragma unroll 4
  for (int k = 0; k < 512; ++k) {
    float w = Wo[k * 512 + col];
#pragma unroll
    for (int r = 0; r < 8; ++r) a[r] += sWl[rh + r][k] * w;
  }
#pragma unroll
  for (int r = 0; r < 8; ++r) Wc[(r0 + rh + r) * 512 + col] = (u16)f2bf_u(a[r]);
  if (c0 == 0) {
    for (int r = 0; r < 16; ++r) {
      float p = 0.f;
      for (int k = tid; k < 512; k += 256) p += sWl[r][k] * bo[k];
      red[tid] = p;
      __syncthreads();
      for (int st = 128; st > 0; st >>= 1) {
        if (tid < st) red[tid] += red[tid + st];
        __syncthreads();
      }
      if (tid == 0) bc[r0 + r] = red[0] + bl[r0 + r];
      __syncthreads();
    }
  }
}

// ---------------------------------------------------------------------------
// gemm_bt: C = A[M,K] * Bt[N,K]^T + bias   (bf16 MFMA 16x16x32)
// 128x128 tile, BK=64, 4 waves, 4x4 acc frags; swizzled LDS; gl_lds16 staging.
// EPI 0: f32 row-major, bias[col]          (final output)
// EPI 1: col<512 -> q row-major bf16; col>=512 -> K packed tiles; bias[col]
//        kpk[h][t/64][t&63][d]  (addr = h*T*64 + (t>>6)*4096 + (t&63)*64 + d)
// EPI 2: V packed tiles, bias[row]
//        vpk[h][t/64][d][t&63]  (addr = h*T*64 + (t>>6)*4096 + d*64 + (t&63))
// ---------------------------------------------------------------------------
template <int EPI>
__global__ __launch_bounds__(256) void gemm_bt(
    const u16* __restrict__ A, const u16* __restrict__ Bt, void* __restrict__ C,
    void* __restrict__ C2, const float* __restrict__ bias, int M, int N, int K) {
  const int nn = N >> 7;
  const int bm = blockIdx.x / nn, bn = blockIdx.x % nn;
  const int tid = threadIdx.x;
  const int w = tid >> 6, lane = tid & 63;
  const int quad = lane >> 4, l16 = lane & 15;
  const int wm = w >> 1, wn = w & 1;
  __shared__ __align__(16) u16 As[128 * 64];
  __shared__ __align__(16) u16 Bs[128 * 64];
  f32x4 acc[4][4];
#pragma unroll
  for (int mi = 0; mi < 4; ++mi)
#pragma unroll
    for (int ni = 0; ni < 4; ++ni) acc[mi][ni] = (f32x4){0.f, 0.f, 0.f, 0.f};
  const int sr = lane >> 3, scn = lane & 7;
  const int rowA0 = bm << 7, rowB0 = bn << 7;
  for (int kt = 0; kt < K; kt += 64) {
#pragma unroll
    for (int u = 0; u < 4; ++u) {
      int rbase = (w << 5) + (u << 3);
      int ml = rbase + sr;
      int ca = scn ^ (ml & 7);
      gl_lds16(A  + (size_t)(rowA0 + ml) * K + kt + ca * 8, As + (rbase << 6));
      gl_lds16(Bt + (size_t)(rowB0 + ml) * K + kt + ca * 8, Bs + (rbase << 6));
    }
    __syncthreads();
#pragma unroll
    for (int ks = 0; ks < 2; ++ks) {
      bf16x8 af[4], bfv[4];
#pragma unroll
      for (int mi = 0; mi < 4; ++mi) {
        int r = (wm << 6) + (mi << 4) + l16;
        af[mi] = *(const bf16x8*)(As + (r << 6) + ((((ks << 2) + quad) ^ (r & 7)) << 3));
      }
#pragma unroll
      for (int ni = 0; ni < 4; ++ni) {
        int r = (wn << 6) + (ni << 4) + l16;
        bfv[ni] = *(const bf16x8*)(Bs + (r << 6) + ((((ks << 2) + quad) ^ (r & 7)) << 3));
      }
#pragma unroll
      for (int mi = 0; mi < 4; ++mi)
#pragma unroll
        for (int ni = 0; ni < 4; ++ni)
          acc[mi][ni] = __builtin_amdgcn_mfma_f32_16x16x32_bf16(af[mi], bfv[ni], acc[mi][ni], 0, 0, 0);
    }
    __syncthreads();
  }
#pragma unroll
  for (int mi = 0; mi < 4; ++mi) {
#pragma unroll
    for (int ni = 0; ni < 4; ++ni) {
      int row = rowA0 + (wm << 6) + (mi << 4) + (quad << 2);
      int col = rowB0 + (wn << 6) + (ni << 4) + l16;
      float bvc = (EPI == 2) ? 0.f : bias[col];
#pragma unroll
      for (int r = 0; r < 4; ++r) {
        float v = acc[mi][ni][r] + ((EPI == 2) ? bias[row + r] : bvc);
        if (EPI == 0) {
          ((float*)C)[(size_t)(row + r) * N + col] = v;
        } else if (EPI == 1) {
          if (col < 512) {
            ((u16*)C)[(size_t)(row + r) * 512 + col] = (u16)f2bf_u(v);
          } else {
            int f = col - 512, hh = f >> 6, d = f & 63, t = row + r;
            ((u16*)C2)[(size_t)hh * (TT * 64) + ((t >> 6) << 12) + ((t & 63) << 6) + d] = (u16)f2bf_u(v);
          }
        } else {
          int f = row + r, hh = f >> 6, d = f & 63, t = col;
          ((u16*)C)[(size_t)hh * (TT * 64) + ((t >> 6) << 12) + (d << 6) + (t & 63)] = (u16)f2bf_u(v);
        }
      }
    }
  }
}

// ---------------------------------------------------------------------------
// attn v3: one block = (q-tile of 128, head). 4 waves, 32 q rows each.
// q: [T][512] pre-scaled (log2-domain scores). K/V from packed per-head
// tiles (8KB, 4KB-aligned) -> low-page-count staging. Double-buffered LDS
// (barrier -> issue next loads -> compute). Static-max softmax: P=exp2(s),
// per-lane l partials, one DPP reduce at the end. Interior iters unmasked.
// ---------------------------------------------------------------------------
__global__ __launch_bounds__(256) void attn_kernel(
    const u16* __restrict__ qb, const u16* __restrict__ kpk,
    const u16* __restrict__ vpk, u16* __restrict__ ctx, const int* __restrict__ seg) {
  const int bx = blockIdx.x;
  if (bx >= seg[0]) return;
  const int h = blockIdx.y;
  const int g = seg[32 + bx], q0 = seg[320 + bx];
  const int s0 = seg[1 + g], len = seg[2 + g] - s0;
  const int tid = threadIdx.x, w = tid >> 6, lane = tid & 63;
  const int quad = lane >> 4, l16 = lane & 15;

  __shared__ __align__(16) u16 Ks[2][64 * 64];
  __shared__ __align__(16) u16 Vs[2][64 * 64];
  __shared__ __align__(16) u16 Ps[4 * 32 * 64];

  const u16* kh = kpk + (size_t)h * (TT * 64);
  const u16* vh = vpk + (size_t)h * (TT * 64);

  // Q fragments (A-layout), 32 rows/wave, zero beyond len
  bf16x8 afq[2][2];
#pragma unroll
  for (int mt = 0; mt < 2; ++mt)
#pragma unroll
    for (int ks = 0; ks < 2; ++ks) {
      int ql = (w << 5) + (mt << 4) + l16;
      uint4 tmp = {0u, 0u, 0u, 0u};
      if (q0 + ql < len)
        tmp = *(const uint4*)(qb + (size_t)(s0 + q0 + ql) * 512 + (h << 6) + (((ks << 2) + quad) << 3));
      afq[mt][ks] = __builtin_bit_cast(bf16x8, tmp);
    }

  f32x4 lrow[2], O[2][4];
#pragma unroll
  for (int mt = 0; mt < 2; ++mt) {
    lrow[mt] = (f32x4){0.f, 0.f, 0.f, 0.f};
#pragma unroll
    for (int dt = 0; dt < 4; ++dt) O[mt][dt] = (f32x4){0.f, 0.f, 0.f, 0.f};
  }
  const int delta = s0 & 7;               // alignment shift of kv window
  const int srl = lane >> 3, sc = lane & 7;
  int vcl = ((len - 8 + delta) & ~7) - delta;   // safe aligned start, +8 <= len
  if (vcl < -delta) vcl = -delta;

  auto stage = [&](int kv0, int b) {
#pragma unroll
    for (int u = 0; u < 2; ++u) {
      const int rb = (w << 4) + (u << 3);
      int r = rb + srl;
      int ca = sc ^ (r & 7);
      // K: Ks[key r][d], token clamp (finite, masked)
      int tr = kv0 + r; tr = tr < len - 1 ? tr : len - 1;
      int tk = s0 + tr;
      gl_lds16(kh + ((tk >> 6) << 12) + ((tk & 63) << 6) + (ca << 3), Ks[b] + (rb << 6));
      // V: Vs[d r][key chunk]; redirect ONLY fully-masked chunks
      int st = kv0 + (ca << 3);
      st = (st < len) ? st : vcl;
      int tv = s0 + st;
      gl_lds16(vh + ((tv >> 6) << 12) + (r << 6) + (tv & 63), Vs[b] + (rb << 6));
    }
  };

  const int nIt = (len + delta + 63) >> 6;
  stage(-delta, 0);
  for (int i = 0; i < nIt; ++i) {
    const int kv0 = -delta + (i << 6);
    __syncthreads();                    // cur buffer landed; prev reads done
    if (i + 1 < nIt) stage(kv0 + 64, (i + 1) & 1);   // prefetch next
    const u16* Kc = Ks[i & 1];
    const u16* Vc = Vs[i & 1];

    // S = Q K^T (pre-scaled, log2 domain)
    f32x4 s[2][4];
#pragma unroll
    for (int mt = 0; mt < 2; ++mt)
#pragma unroll
      for (int nt = 0; nt < 4; ++nt) s[mt][nt] = (f32x4){0.f, 0.f, 0.f, 0.f};
#pragma unroll
    for (int ks = 0; ks < 2; ++ks) {
      bf16x8 bk[4];
#pragma unroll
      for (int nt = 0; nt < 4; ++nt) {
        int kr = (nt << 4) + l16;
        bk[nt] = *(const bf16x8*)(Kc + (kr << 6) + ((((ks << 2) + quad) ^ (kr & 7)) << 3));
      }
#pragma unroll
      for (int mt = 0; mt < 2; ++mt)
#pragma unroll
        for (int nt = 0; nt < 4; ++nt)
          s[mt][nt] = __builtin_amdgcn_mfma_f32_16x16x32_bf16(afq[mt][ks], bk[nt], s[mt][nt], 0, 0, 0);
    }
    // key mask only on edge iterations (wave-uniform branch)
    if ((kv0 < 0) | (kv0 + 64 > len)) {
#pragma unroll
      for (int nt = 0; nt < 4; ++nt) {
        int ki = kv0 + (nt << 4) + l16;
        float msk = ((unsigned)ki < (unsigned)len) ? 0.f : -1e30f;
#pragma unroll
        for (int mt = 0; mt < 2; ++mt)
#pragma unroll
          for (int r = 0; r < 4; ++r) s[mt][nt][r] += msk;
      }
    }
    // P = exp2(s); per-lane l partials; pack P -> LDS (A-layout, swizzled)
#pragma unroll
    for (int mt = 0; mt < 2; ++mt) {
#pragma unroll
      for (int nt = 0; nt < 4; ++nt)
#pragma unroll
        for (int r = 0; r < 4; ++r) s[mt][nt][r] = __builtin_amdgcn_exp2f(s[mt][nt][r]);
#pragma unroll
      for (int r = 0; r < 4; ++r)
        lrow[mt][r] += (s[mt][0][r] + s[mt][1][r]) + (s[mt][2][r] + s[mt][3][r]);
      u16* Pw = Ps + (w << 11) + (mt << 10);
#pragma unroll
      for (int nt = 0; nt < 4; ++nt)
#pragma unroll
        for (int r = 0; r < 4; ++r) {
          unsigned a = f2bf_u(s[mt][nt][r]);
          unsigned b = (unsigned)__builtin_amdgcn_mov_dpp((int)a, 0xB1, 0xF, 0xF, true);
          if (!(l16 & 1)) {
            int prow = (quad << 2) + r, kc = (nt << 4) + l16;
            *(u32*)(Pw + (prow << 6) + (((kc >> 3) ^ (prow & 7)) << 3) + (kc & 7)) = (b << 16) | a;
          }
        }
    }
    // O += P V  (same-wave LDS roundtrip, DS in-order, no barrier)
#pragma unroll
    for (int ks = 0; ks < 2; ++ks) {
      bf16x8 bv[4], ap[2];
#pragma unroll
      for (int dt = 0; dt < 4; ++dt) {
        int vr = (dt << 4) + l16;
        bv[dt] = *(const bf16x8*)(Vc + (vr << 6) + ((((ks << 2) + quad) ^ (vr & 7)) << 3));
      }
#pragma unroll
      for (int mt = 0; mt < 2; ++mt)
        ap[mt] = *(const bf16x8*)(Ps + (w << 11) + (mt << 10) + (l16 << 6) + ((((ks << 2) + quad) ^ (l16 & 7)) << 3));
#pragma unroll
      for (int mt = 0; mt < 2; ++mt)
#pragma unroll
        for (int dt = 0; dt < 4; ++dt)
          O[mt][dt] = __builtin_amdgcn_mfma_f32_16x16x32_bf16(ap[mt], bv[dt], O[mt][dt], 0, 0, 0);
    }
  }

  // final l reduction (one DPP butterfly), normalize, store
#pragma unroll
  for (int mt = 0; mt < 2; ++mt) {
    f32x4 inv;
#pragma unroll
    for (int r = 0; r < 4; ++r) {
      float t = lrow[mt][r];
      t += dppf<0xB1>(t);
      t += dppf<0x4E>(t);
      t += dppf<0x124>(t);
      t += dppf<0x128>(t);
      inv[r] = 1.f / t;
    }
#pragma unroll
    for (int dt = 0; dt < 4; ++dt)
#pragma unroll
      for (int r = 0; r < 4; ++r) {
        int ql = (w << 5) + (mt << 4) + (quad << 2) + r;
        if (q0 + ql < len)
          ctx[(size_t)(s0 + q0 + ql) * 512 + (h << 6) + (dt << 4) + l16] = (u16)f2bf_u(O[mt][dt][r] * inv[r]);
      }
  }
}

// ---------------------------------------------------------------------------
extern "C" void kernel_launch(void* const* d_in, const int* in_sizes, int n_in,
                              void* d_out, int out_size, void* d_ws, size_t ws_size,
                              hipStream_t stream) {
  const float* x = (const float*)d_in[0];
  const int* batch = (const int*)d_in[1];   // harness passes integers as int32
  const float* ipw = (const float*)d_in[2];
  const float* ipb = (const float*)d_in[3];
  const float* opw = (const float*)d_in[4];
  const float* opb = (const float*)d_in[5];
  const float* lw = (const float*)d_in[6];
  const float* lb = (const float*)d_in[7];
  float* out = (float*)d_out;
  char* ws = (char*)d_ws;

  u16* xb   = (u16*)(ws + 0);              // 16 MB (x bf16)
  u16* ctxb = (u16*)(ws + 0);              // aliases xb (disjoint liveness)
  u16* qb   = (u16*)(ws + 16777216);       // 16 MB: [T][512] q (pre-scaled)
  u16* kpk  = (u16*)(ws + 33554432);       // 16 MB: packed K tiles
  u16* vpk  = (u16*)(ws + 50331648);       // 16 MB: packed V tiles
  u16* ipwb = (u16*)(ws + 67108864);       // 1.5 MB
  u16* wcb  = (u16*)(ws + 68681728);       // 0.5 MB
  float* bc = (float*)(ws + 69206016);     // 2 KB
  float* bqk= (float*)(ws + 69208064);     // 4 KB
  int* seg  = (int*)(ws + 69212160);       // 4 KB

  prep_kernel<<<1121, 256, 0, stream>>>(x, ipw, batch, ipb, xb, ipwb, bqk, seg);
  wc_kernel<<<128, 256, 0, stream>>>(lw, opw, opb, lb, wcb, bc);
  // Q (row-major, pre-scaled) + K (packed tiles) = X * Wqk^T + bqk
  gemm_bt<1><<<128 * 8, 256, 0, stream>>>(xb, ipwb, qb, kpk, bqk, TT, 1024, 512);
  // V packed tiles = Wv * X^T + bv[row]
  gemm_bt<2><<<4 * 128, 256, 0, stream>>>(ipwb + 1024 * 512, xb, vpk, nullptr, ipb + 1024, 512, TT, 512);
  attn_kernel<<<dim3(MAXT, 8), 256, 0, stream>>>(qb, kpk, vpk, ctxb, seg);
  gemm_bt<0><<<128 * 4, 256, 0, stream>>>(ctxb, wcb, out, nullptr, bc, TT, 512, 512);
  (void)in_sizes; (void)n_in; (void)out_size; (void)ws_size;
}